// Round 1
// baseline (737.560 us; speedup 1.0000x reference)
//
#include <hip/hip_runtime.h>

// Problem constants (from reference)
#define IM_H 128
#define IM_W 128
#define HT_H 184
#define HT_W 180
#define NBINS (HT_H * HT_W)       // 33120
#define NPIX  (IM_H * IM_W)       // 16384
#define NMAPS 32                  // b*c = 2*16
#define NV    4000000
#define CHUNKS 8
#define TPB 1024
#define INV_NORM (1.0f / 128.0f)  // 1/max(IM_H, IM_W)

// One block = (map, vote-chunk). Full-resolution fp32 histogram in LDS
// (33120 * 4 B = 132.5 KB <= 160 KB gfx950 LDS => 1 block/CU, 16 waves).
__global__ __launch_bounds__(TPB) void ht_vote_kernel(
    const float* __restrict__ x,
    const int*   __restrict__ vp,
    const int*   __restrict__ vb,
    const float* __restrict__ vw,
    float*       __restrict__ out) {
  __shared__ float hist[NBINS];

  // zero LDS histogram
  for (int i = threadIdx.x; i < NBINS; i += TPB) hist[i] = 0.0f;
  __syncthreads();

  const int map   = blockIdx.x >> 3;   // 0..31
  const int chunk = blockIdx.x & 7;    // 0..7
  const float* xm = x + map * NPIX;

  const int per   = NV / CHUNKS;       // 500000 (divisible by 4)
  const int start = chunk * per;
  const int end   = start + per;

  // 4 votes per thread-iteration: vectorized coalesced stream loads
  for (int i = start + threadIdx.x * 4; i < end; i += TPB * 4) {
    const int4   p = *reinterpret_cast<const int4*>(vp + i);
    const int4   b = *reinterpret_cast<const int4*>(vb + i);
    const float4 w = *reinterpret_cast<const float4*>(vw + i);

    float g0 = xm[p.x] * w.x;
    float g1 = xm[p.y] * w.y;
    float g2 = xm[p.z] * w.z;
    float g3 = xm[p.w] * w.w;

    __hip_atomic_fetch_add(&hist[b.x], g0, __ATOMIC_RELAXED, __HIP_MEMORY_SCOPE_WORKGROUP);
    __hip_atomic_fetch_add(&hist[b.y], g1, __ATOMIC_RELAXED, __HIP_MEMORY_SCOPE_WORKGROUP);
    __hip_atomic_fetch_add(&hist[b.z], g2, __ATOMIC_RELAXED, __HIP_MEMORY_SCOPE_WORKGROUP);
    __hip_atomic_fetch_add(&hist[b.w], g3, __ATOMIC_RELAXED, __HIP_MEMORY_SCOPE_WORKGROUP);
  }
  __syncthreads();

  // flush: coalesced contiguous global fp32 atomics (8 chunks collide per bin)
  float* om = out + map * NBINS;
  for (int i = threadIdx.x; i < NBINS; i += TPB) {
    __hip_atomic_fetch_add(&om[i], hist[i] * INV_NORM, __ATOMIC_RELAXED, __HIP_MEMORY_SCOPE_AGENT);
  }
}

extern "C" void kernel_launch(void* const* d_in, const int* in_sizes, int n_in,
                              void* d_out, int out_size, void* d_ws, size_t ws_size,
                              hipStream_t stream) {
  const float* x  = (const float*)d_in[0];  // [2,16,128,128] fp32
  const int*   vp = (const int*)d_in[1];    // [4M] pixel idx
  const int*   vb = (const int*)d_in[2];    // [4M] bin idx
  const float* vw = (const float*)d_in[3];  // [4M] weight

  float* out = (float*)d_out;               // [2,16,184,180] fp32

  // d_out is poisoned 0xAA before every launch — zero it (memset node is
  // graph-capture safe; harness itself uses hipMemsetAsync).
  hipMemsetAsync(out, 0, (size_t)out_size * sizeof(float), stream);

  ht_vote_kernel<<<NMAPS * CHUNKS, TPB, 0, stream>>>(x, vp, vb, vw, out);
}